// Round 25
// baseline (138.349 us; speedup 1.0000x reference)
//
#include <hip/hip_runtime.h>
#include <stdint.h>

#define BB 4
#define NN 2048
#define FIN 256
#define FOUT 128
#define NH 4
#define NEG_SLOPE 0.2f

typedef short bf16x8 __attribute__((ext_vector_type(8)));
typedef unsigned short u16x8 __attribute__((ext_vector_type(8)));
typedef float f32x4 __attribute__((ext_vector_type(4)));
typedef unsigned long long u64;

__device__ inline float b2f(unsigned short u) {
    union { unsigned int i; float f; } x; x.i = ((unsigned int)u) << 16; return x.f;
}
__device__ inline unsigned short f2b(float f) {   // fp32 -> bf16 RNE
    union { float f; unsigned int i; } x; x.f = f;
    unsigned int r = x.i + 0x7fffu + ((x.i >> 16) & 1u);
    return (unsigned short)(r >> 16);
}
__device__ inline unsigned short f2b_fast(float f) {  // round-half-up (f >= 0 here)
    union { float f; unsigned int i; } x; x.f = f;
    return (unsigned short)((x.i + 0x8000u) >> 16);
}

// ---------------------------------------------------------------------------
// NOTE (timing model, R5): the harness's workspace poison-fill (~43 µs) runs
// INSIDE the timed window. Controllable budget = dur - 43.
// NOTE (R2): no cross-block fences (device-scope threadfence cost ~120 µs).
// NOTE (R10): A built in fragment registers (LDS A-tiles = 1KB read/MFMA).
// NOTE (R16/R17): ER broadcast needs a BIJECTIVE XOR skew.
// NOTE (R21): unified VGPR+AGPR budget 256/lane at (512,2); v5 sits AT it.
// Forced B-double-buffer (+64 VGPR) spilled (WRITE 4->62MB, 44->72µs).
// NOTE (R23): bf16-packed ER regressed (dependent unpack VALU). Only
// serial-chain cuts or occupancy help in this latency-bound regime.
// NOTE (R24): this = banked-best (125.2 µs, reproduced twice) + ONE change:
// `#pragma unroll 2` on the k2 main loop — compiler-owned partial software
// pipelining within the register budget (vs R18's forced explicit buffers).
// ---------------------------------------------------------------------------

// ---------------------------------------------------------------------------
// k0_prep: W fp32 -> bf16 hi/lo split only (mask pack lives in k1).
// ---------------------------------------------------------------------------
__global__ __launch_bounds__(256) void k0_prep(const float* __restrict__ Ww,
                                               unsigned short* __restrict__ Whi,
                                               unsigned short* __restrict__ Wlo) {
    int idx = blockIdx.x * 256 + threadIdx.x;   // 32768 elems
    float v = Ww[idx];
    unsigned short hb = f2b(v);
    Whi[idx] = hb;
    Wlo[idx] = f2b(v - b2f(hb));
}

// ---------------------------------------------------------------------------
// K1 (MFMA): blocks [0,512): Wh tile + WhT/EL/ER tables.
// blocks [512, 512+NN): adj row -> 32 u64 bitmask words (overlaps Wh compute).
// ---------------------------------------------------------------------------
__global__ __launch_bounds__(256) void k1_wh(
    const float* __restrict__ h, const unsigned short* __restrict__ Whi,
    const unsigned short* __restrict__ Wlo, const float* __restrict__ Wb,
    const float* __restrict__ attw, unsigned short* __restrict__ WhT,
    float2* __restrict__ ELpair, float2* __restrict__ ERf,
    const int* __restrict__ adj, u64* __restrict__ mask) {
    if (blockIdx.x >= BB * NN / 16) {            // ---- mask-pack blocks
        int row = blockIdx.x - BB * NN / 16;
        int wave = threadIdx.x >> 6, lane = threadIdx.x & 63;
        #pragma unroll
        for (int it = 0; it < 8; ++it) {
            int w = it * 4 + wave;
            int j = w * 64 + lane;
            u64 mm = __ballot(adj[(size_t)row * NN + j] != 0);
            if (lane == 0) mask[row * 32 + w] = mm;
        }
        return;
    }
    __shared__ unsigned short Ahi[16][264];
    __shared__ unsigned short Alo[16][264];
    __shared__ float whs[16][132];
    int t = threadIdx.x;
    int b = blockIdx.x >> 7;
    int n0 = (blockIdx.x & 127) * 16;
    {
        int r = t >> 4, c = (t & 15) * 16;
        const float* hp = h + ((size_t)(b * NN + n0 + r)) * FIN + c;
        u16x8 hi0, hi1, lo0, lo1;
        #pragma unroll
        for (int q = 0; q < 4; ++q) {
            float4 v = *(const float4*)(hp + q * 4);
            float vv[4] = {v.x, v.y, v.z, v.w};
            #pragma unroll
            for (int e = 0; e < 4; ++e) {
                int idx = q * 4 + e;
                unsigned short hb = f2b(vv[e]);
                unsigned short lb = f2b(vv[e] - b2f(hb));
                if (idx < 8) { hi0[idx] = (short)hb; lo0[idx] = (short)lb; }
                else         { hi1[idx - 8] = (short)hb; lo1[idx - 8] = (short)lb; }
            }
        }
        *(u16x8*)&Ahi[r][c] = *(u16x8*)&hi0;
        *(u16x8*)&Ahi[r][c + 8] = *(u16x8*)&hi1;
        *(u16x8*)&Alo[r][c] = *(u16x8*)&lo0;
        *(u16x8*)&Alo[r][c + 8] = *(u16x8*)&lo1;
    }
    __syncthreads();
    int lane = t & 63, wv = t >> 6;
    int m = lane & 15, quad = lane >> 4;
    int o0 = wv * 32;
    f32x4 acc0 = {0.f, 0.f, 0.f, 0.f}, acc1 = {0.f, 0.f, 0.f, 0.f};
    const unsigned short* wh0 = Whi + (size_t)(o0 + m) * FIN;
    const unsigned short* wl0 = Wlo + (size_t)(o0 + m) * FIN;
    const unsigned short* wh1 = Whi + (size_t)(o0 + 16 + m) * FIN;
    const unsigned short* wl1 = Wlo + (size_t)(o0 + 16 + m) * FIN;
    #pragma unroll
    for (int ks = 0; ks < 8; ++ks) {
        int ko = ks * 32 + quad * 8;
        bf16x8 ahi = *(bf16x8*)&Ahi[m][ko];
        bf16x8 alo = *(bf16x8*)&Alo[m][ko];
        bf16x8 bh0 = *(const bf16x8*)(wh0 + ko);
        bf16x8 bl0 = *(const bf16x8*)(wl0 + ko);
        bf16x8 bh1 = *(const bf16x8*)(wh1 + ko);
        bf16x8 bl1 = *(const bf16x8*)(wl1 + ko);
        acc0 = __builtin_amdgcn_mfma_f32_16x16x32_bf16(ahi, bh0, acc0, 0, 0, 0);
        acc0 = __builtin_amdgcn_mfma_f32_16x16x32_bf16(ahi, bl0, acc0, 0, 0, 0);
        acc0 = __builtin_amdgcn_mfma_f32_16x16x32_bf16(alo, bh0, acc0, 0, 0, 0);
        acc1 = __builtin_amdgcn_mfma_f32_16x16x32_bf16(ahi, bh1, acc1, 0, 0, 0);
        acc1 = __builtin_amdgcn_mfma_f32_16x16x32_bf16(ahi, bl1, acc1, 0, 0, 0);
        acc1 = __builtin_amdgcn_mfma_f32_16x16x32_bf16(alo, bh1, acc1, 0, 0, 0);
    }
    float bias0 = Wb[o0 + m], bias1 = Wb[o0 + 16 + m];
    #pragma unroll
    for (int reg = 0; reg < 4; ++reg) {
        int row = quad * 4 + reg;
        whs[row][o0 + m] = acc0[reg] + bias0;
        whs[row][o0 + 16 + m] = acc1[reg] + bias1;
    }
    __syncthreads();
    {   // WhT writer: 2 threads per o, 8 n each
        int o = t >> 1, half = t & 1;
        u16x8 v8;
        #pragma unroll
        for (int r = 0; r < 8; ++r) v8[r] = (short)f2b(whs[half * 8 + r][o]);
        *(u16x8*)(WhT + (size_t)(b * FOUT + o) * NN + n0 + half * 8) = v8;
    }
    {   // e-dots + exp tables
        int outi = t >> 1, half = t & 1;
        int i = outi >> 3, d = outi & 7, hh = d & 3, side = d >> 2;
        const float* arow = attw + hh * (2 * FOUT) + side * FOUT + half * 64;
        float s = 0.f;
        #pragma unroll 8
        for (int k = 0; k < 64; ++k) s = fmaf(whs[i][half * 64 + k], arow[k], s);
        s += __shfl_xor(s, 1);
        if (half == 0) {
            float p = __expf(s), n = __expf(NEG_SLOPE * s);
            if (side == 0) {
                ELpair[(size_t)(b * NH + hh) * NN + n0 + i] = make_float2(p, n);
            } else {
                ERf[((size_t)b * NN + n0 + i) * NH + hh] = make_float2(p, n);
            }
        }
    }
}

// ---------------------------------------------------------------------------
// K2 v5u2 = measured-best v5 + `#pragma unroll 2` on the main loop (the ONLY
// change): lets the compiler hoist iter i+1's independent B-loads/ds_reads
// above iter i's MFMA cluster within the register budget.
// waves = (isub 2) x (kp 4); each wave owns 16 i-rows x ALL 128 o
// (8 B-frags) x ks = kp, kp+4, ... (16 iters). ERf LDS: bijective XOR skew.
// Denominators via ones-MFMA. Tail: 4-way kp reduce through reused LDS.
// grid (NN/32, BB) = 256 blocks x 512 thr.
// ---------------------------------------------------------------------------
__global__ __launch_bounds__(512, 2) void k2_reg(
    const unsigned short* __restrict__ WhT, const float2* __restrict__ ERf,
    const float2* __restrict__ ELpair, const u64* __restrict__ mask,
    float* __restrict__ out) {
    __shared__ char smem[65600 + 8448 + 1536];   // 73.8 KB
    float4* erf4 = (float4*)smem;                // XOR-skewed [4096] float4
    u64* mlds = (u64*)(smem + 65600);            // [32][33] padded
    float* sred = (float*)(smem + 65600 + 8448); // [3kp'][2isub][4h][4r][4quad]
    int t = threadIdx.x;
    int b = blockIdx.y, i0 = blockIdx.x * 32;
    int lane = t & 63, wv = t >> 6;
    int m = lane & 15, quad = lane >> 4;
    int isub = wv & 1, kp = wv >> 1;             // kp in 0..3

    {   // stage ERf for this b (bijective XOR-skewed destination)
        const float4* src = (const float4*)(ERf + (size_t)b * NN * NH);
        #pragma unroll
        for (int i = 0; i < 8; ++i) {
            int g = t + i * 512;
            erf4[g ^ (((g >> 4) & 3) << 1)] = src[g];
        }
    }
    {   // stage masks: 32 rows x 32 words, padded stride 33
        #pragma unroll
        for (int i = 0; i < 2; ++i) {
            int idx = t + i * 512;
            int r = idx >> 5, w = idx & 31;
            mlds[r * 33 + w] = mask[(size_t)(i0 + r) * 32 + w];
        }
    }
    int irow = i0 + isub * 16 + m;               // this lane's A row
    float elp[NH], eln[NH];
    #pragma unroll
    for (int hh = 0; hh < NH; ++hh) {
        float2 e2 = ELpair[(size_t)(b * NH + hh) * NN + irow];
        elp[hh] = e2.x; eln[hh] = e2.y;
    }
    __syncthreads();

    bf16x8 ones;
    #pragma unroll
    for (int e = 0; e < 8; ++e) ones[e] = (short)0x3F80;   // bf16 1.0

    const unsigned short* bp[8];
    #pragma unroll
    for (int f = 0; f < 8; ++f)
        bp[f] = WhT + (size_t)(b * FOUT + f * 16 + m) * NN + kp * 32 + quad * 8;

    f32x4 acc[8][NH];                            // [o-frag f][head h]
    f32x4 sacc[NH];                              // [head h] denominator
    #pragma unroll
    for (int f = 0; f < 8; ++f)
        #pragma unroll
        for (int hh = 0; hh < NH; ++hh) acc[f][hh] = (f32x4){0.f, 0.f, 0.f, 0.f};
    #pragma unroll
    for (int hh = 0; hh < NH; ++hh) sacc[hh] = (f32x4){0.f, 0.f, 0.f, 0.f};

    int mr = isub * 16 + m;                      // local mask row
    int qs = quad << 1;                          // XOR skew for reads

    #pragma unroll 2
    for (int it = 0; it < 16; ++it) {
        int ks = (it << 2) | kp;
        int jb = ks * 32 + quad * 8;             // lane's 8-j window
        bf16x8 bfr[8];
        #pragma unroll
        for (int f = 0; f < 8; ++f) bfr[f] = *(const bf16x8*)(bp[f]);
        u64 w64 = mlds[mr * 33 + (ks >> 1)];
        unsigned mb = (unsigned)(w64 >> (((ks & 1) << 5) + (quad << 3))) & 0xFFu;
        int gb = jb * 2;                         // unskewed float4 base (mod16==0)
        bf16x8 af0, af1, af2, af3;
        #pragma unroll
        for (int e = 0; e < 8; ++e) {
            int a0 = (gb + e * 2) ^ qs;          // (g>>4)&3 == quad here
            float4 e0 = erf4[a0];                // h0p h0n h1p h1n
            float4 e1 = erf4[a0 + 1];            // h2p h2n h3p h3n
            bool bit = (mb >> e) & 1u;
            float w0 = fmaxf(elp[0] * e0.x, eln[0] * e0.y);
            float w1 = fmaxf(elp[1] * e0.z, eln[1] * e0.w);
            float w2 = fmaxf(elp[2] * e1.x, eln[2] * e1.y);
            float w3 = fmaxf(elp[3] * e1.z, eln[3] * e1.w);
            af0[e] = bit ? (short)f2b_fast(w0) : (short)0;
            af1[e] = bit ? (short)f2b_fast(w1) : (short)0;
            af2[e] = bit ? (short)f2b_fast(w2) : (short)0;
            af3[e] = bit ? (short)f2b_fast(w3) : (short)0;
        }
        sacc[0] = __builtin_amdgcn_mfma_f32_16x16x32_bf16(af0, ones, sacc[0], 0, 0, 0);
        sacc[1] = __builtin_amdgcn_mfma_f32_16x16x32_bf16(af1, ones, sacc[1], 0, 0, 0);
        sacc[2] = __builtin_amdgcn_mfma_f32_16x16x32_bf16(af2, ones, sacc[2], 0, 0, 0);
        sacc[3] = __builtin_amdgcn_mfma_f32_16x16x32_bf16(af3, ones, sacc[3], 0, 0, 0);
        #pragma unroll
        for (int f = 0; f < 8; ++f) {
            acc[f][0] = __builtin_amdgcn_mfma_f32_16x16x32_bf16(af0, bfr[f], acc[f][0], 0, 0, 0);
            acc[f][1] = __builtin_amdgcn_mfma_f32_16x16x32_bf16(af1, bfr[f], acc[f][1], 0, 0, 0);
            acc[f][2] = __builtin_amdgcn_mfma_f32_16x16x32_bf16(af2, bfr[f], acc[f][2], 0, 0, 0);
            acc[f][3] = __builtin_amdgcn_mfma_f32_16x16x32_bf16(af3, bfr[f], acc[f][3], 0, 0, 0);
        }
        #pragma unroll
        for (int f = 0; f < 8; ++f) bp[f] += 128;
    }
    __syncthreads();                             // ERf reads done; reuse smem

    // ---- tail: 4-way kp reduction. red reuses erf4 region (48 KB).
    float* red = (float*)smem;                   // [3kp'][2isub][8f][4r][64]
    if (kp && m == 0) {
        #pragma unroll
        for (int hh = 0; hh < NH; ++hh)
            #pragma unroll
            for (int r = 0; r < 4; ++r)
                sred[(((kp - 1) * 2 + isub) * 16 + hh * 4 + r) * 4 + quad] = sacc[hh][r];
    }
    float v[8][4], inv[4][4];
    #pragma unroll
    for (int hh = 0; hh < NH; ++hh) {
        if (kp) {
            #pragma unroll
            for (int f = 0; f < 8; ++f)
                #pragma unroll
                for (int r = 0; r < 4; ++r)
                    red[((((kp - 1) * 2 + isub) * 8 + f) * 4 + r) * 64 + lane] = acc[f][hh][r];
        }
        __syncthreads();
        if (kp == 0) {
            if (hh == 0) {
                #pragma unroll
                for (int h2 = 0; h2 < NH; ++h2)
                    #pragma unroll
                    for (int r = 0; r < 4; ++r) {
                        float S = sacc[h2][r];
                        #pragma unroll
                        for (int k2 = 0; k2 < 3; ++k2)
                            S += sred[((k2 * 2 + isub) * 16 + h2 * 4 + r) * 4 + quad];
                        inv[h2][r] = (S > 0.f) ? 1.f / S : 0.f;
                    }
            }
            #pragma unroll
            for (int f = 0; f < 8; ++f)
                #pragma unroll
                for (int r = 0; r < 4; ++r) {
                    float tot = acc[f][hh][r];
                    #pragma unroll
                    for (int k2 = 0; k2 < 3; ++k2)
                        tot += red[(((k2 * 2 + isub) * 8 + f) * 4 + r) * 64 + lane];
                    float t2 = tot * inv[hh][r];
                    if (hh == 0) v[f][r] = t2; else v[f][r] += t2;
                }
        }
        __syncthreads();
    }
    if (kp == 0) {
        #pragma unroll
        for (int r = 0; r < 4; ++r) {
            int orow = i0 + isub * 16 + quad * 4 + r;
            #pragma unroll
            for (int f = 0; f < 8; ++f)
                out[((size_t)b * NN + orow) * FOUT + f * 16 + m] =
                    fmaxf(0.25f * v[f][r], 0.f);
        }
    }
}

extern "C" void kernel_launch(void* const* d_in, const int* in_sizes, int n_in,
                              void* d_out, int out_size, void* d_ws, size_t ws_size,
                              hipStream_t stream) {
    const float* h    = (const float*)d_in[0];
    const int* adj    = (const int*)d_in[1];
    const float* Ww   = (const float*)d_in[2];
    const float* Wb   = (const float*)d_in[3];
    const float* attw = (const float*)d_in[4];
    float* out = (float*)d_out;
    char* ws = (char*)d_ws;
    // workspace layout (~3.3 MB)
    unsigned short* Whi = (unsigned short*)(ws);                 // 64 KB
    unsigned short* Wlo = (unsigned short*)(ws + 65536);         // 64 KB
    unsigned short* WhT = (unsigned short*)(ws + 131072);        // 2 MB [b][o][n] bf16
    float2*       ELpair = (float2*)(ws + 2228224);              // 256 KB [bh][i]
    float2*       ERf    = (float2*)(ws + 2490368);              // 256 KB [b][j][h] f32 pair
    u64*          mask   = (u64*)(ws + 2752512);                 // 512 KB

    k0_prep<<<dim3(128), dim3(256), 0, stream>>>(Ww, Whi, Wlo);
    k1_wh<<<dim3(BB * NN / 16 + NN), dim3(256), 0, stream>>>(h, Whi, Wlo, Wb, attw,
                                                             WhT, ELpair, ERf,
                                                             adj, mask);
    k2_reg<<<dim3(NN / 32, BB), dim3(512), 0, stream>>>(WhT, ERf, ELpair,
                                                        mask, out);
}

// Round 27
// 125.800 us; speedup vs baseline: 1.0997x; 1.0997x over previous
//
#include <hip/hip_runtime.h>
#include <stdint.h>

#define BB 4
#define NN 2048
#define FIN 256
#define FOUT 128
#define NH 4
#define NEG_SLOPE 0.2f

typedef short bf16x8 __attribute__((ext_vector_type(8)));
typedef unsigned short u16x8 __attribute__((ext_vector_type(8)));
typedef float f32x4 __attribute__((ext_vector_type(4)));
typedef unsigned long long u64;

__device__ inline float b2f(unsigned short u) {
    union { unsigned int i; float f; } x; x.i = ((unsigned int)u) << 16; return x.f;
}
__device__ inline unsigned short f2b(float f) {   // fp32 -> bf16 RNE
    union { float f; unsigned int i; } x; x.f = f;
    unsigned int r = x.i + 0x7fffu + ((x.i >> 16) & 1u);
    return (unsigned short)(r >> 16);
}
__device__ inline unsigned short f2b_fast(float f) {  // round-half-up (f >= 0 here)
    union { float f; unsigned int i; } x; x.f = f;
    return (unsigned short)((x.i + 0x8000u) >> 16);
}

// ---------------------------------------------------------------------------
// BANKED BEST (reproduced twice: 125.39 µs R18, 125.17 µs R24).
// NOTE (timing model, R5): the harness's workspace poison-fill (~43 µs) runs
// INSIDE the timed window. Controllable budget = dur - 43.
// NOTE (R2): no cross-block fences (device-scope threadfence cost ~120 µs).
// NOTE (R10): A built in fragment registers (LDS A-tiles = 1KB read/MFMA).
// NOTE (R16/R17): ER broadcast needs a BIJECTIVE XOR skew.
// NOTE (R21/R23/R25): k2 is latency-bound at the 256-reg unified budget —
// 128 AGPR acc + 128 VGPR leaves ZERO headroom. All three pipelining probes
// spilled or lengthened the dependent chain: forced dbuf (44->72µs),
// packed ER (44->61µs), compiler unroll-2 (44->54µs). Do not re-attempt
// pipelining at this tiling.
// ---------------------------------------------------------------------------

// ---------------------------------------------------------------------------
// k0_prep: W fp32 -> bf16 hi/lo split only (mask pack lives in k1).
// ---------------------------------------------------------------------------
__global__ __launch_bounds__(256) void k0_prep(const float* __restrict__ Ww,
                                               unsigned short* __restrict__ Whi,
                                               unsigned short* __restrict__ Wlo) {
    int idx = blockIdx.x * 256 + threadIdx.x;   // 32768 elems
    float v = Ww[idx];
    unsigned short hb = f2b(v);
    Whi[idx] = hb;
    Wlo[idx] = f2b(v - b2f(hb));
}

// ---------------------------------------------------------------------------
// K1 (MFMA): blocks [0,512): Wh tile + WhT/EL/ER tables.
// blocks [512, 512+NN): adj row -> 32 u64 bitmask words (overlaps Wh compute).
// ---------------------------------------------------------------------------
__global__ __launch_bounds__(256) void k1_wh(
    const float* __restrict__ h, const unsigned short* __restrict__ Whi,
    const unsigned short* __restrict__ Wlo, const float* __restrict__ Wb,
    const float* __restrict__ attw, unsigned short* __restrict__ WhT,
    float2* __restrict__ ELpair, float2* __restrict__ ERf,
    const int* __restrict__ adj, u64* __restrict__ mask) {
    if (blockIdx.x >= BB * NN / 16) {            // ---- mask-pack blocks
        int row = blockIdx.x - BB * NN / 16;
        int wave = threadIdx.x >> 6, lane = threadIdx.x & 63;
        #pragma unroll
        for (int it = 0; it < 8; ++it) {
            int w = it * 4 + wave;
            int j = w * 64 + lane;
            u64 mm = __ballot(adj[(size_t)row * NN + j] != 0);
            if (lane == 0) mask[row * 32 + w] = mm;
        }
        return;
    }
    __shared__ unsigned short Ahi[16][264];
    __shared__ unsigned short Alo[16][264];
    __shared__ float whs[16][132];
    int t = threadIdx.x;
    int b = blockIdx.x >> 7;
    int n0 = (blockIdx.x & 127) * 16;
    {
        int r = t >> 4, c = (t & 15) * 16;
        const float* hp = h + ((size_t)(b * NN + n0 + r)) * FIN + c;
        u16x8 hi0, hi1, lo0, lo1;
        #pragma unroll
        for (int q = 0; q < 4; ++q) {
            float4 v = *(const float4*)(hp + q * 4);
            float vv[4] = {v.x, v.y, v.z, v.w};
            #pragma unroll
            for (int e = 0; e < 4; ++e) {
                int idx = q * 4 + e;
                unsigned short hb = f2b(vv[e]);
                unsigned short lb = f2b(vv[e] - b2f(hb));
                if (idx < 8) { hi0[idx] = (short)hb; lo0[idx] = (short)lb; }
                else         { hi1[idx - 8] = (short)hb; lo1[idx - 8] = (short)lb; }
            }
        }
        *(u16x8*)&Ahi[r][c] = *(u16x8*)&hi0;
        *(u16x8*)&Ahi[r][c + 8] = *(u16x8*)&hi1;
        *(u16x8*)&Alo[r][c] = *(u16x8*)&lo0;
        *(u16x8*)&Alo[r][c + 8] = *(u16x8*)&lo1;
    }
    __syncthreads();
    int lane = t & 63, wv = t >> 6;
    int m = lane & 15, quad = lane >> 4;
    int o0 = wv * 32;
    f32x4 acc0 = {0.f, 0.f, 0.f, 0.f}, acc1 = {0.f, 0.f, 0.f, 0.f};
    const unsigned short* wh0 = Whi + (size_t)(o0 + m) * FIN;
    const unsigned short* wl0 = Wlo + (size_t)(o0 + m) * FIN;
    const unsigned short* wh1 = Whi + (size_t)(o0 + 16 + m) * FIN;
    const unsigned short* wl1 = Wlo + (size_t)(o0 + 16 + m) * FIN;
    #pragma unroll
    for (int ks = 0; ks < 8; ++ks) {
        int ko = ks * 32 + quad * 8;
        bf16x8 ahi = *(bf16x8*)&Ahi[m][ko];
        bf16x8 alo = *(bf16x8*)&Alo[m][ko];
        bf16x8 bh0 = *(const bf16x8*)(wh0 + ko);
        bf16x8 bl0 = *(const bf16x8*)(wl0 + ko);
        bf16x8 bh1 = *(const bf16x8*)(wh1 + ko);
        bf16x8 bl1 = *(const bf16x8*)(wl1 + ko);
        acc0 = __builtin_amdgcn_mfma_f32_16x16x32_bf16(ahi, bh0, acc0, 0, 0, 0);
        acc0 = __builtin_amdgcn_mfma_f32_16x16x32_bf16(ahi, bl0, acc0, 0, 0, 0);
        acc0 = __builtin_amdgcn_mfma_f32_16x16x32_bf16(alo, bh0, acc0, 0, 0, 0);
        acc1 = __builtin_amdgcn_mfma_f32_16x16x32_bf16(ahi, bh1, acc1, 0, 0, 0);
        acc1 = __builtin_amdgcn_mfma_f32_16x16x32_bf16(ahi, bl1, acc1, 0, 0, 0);
        acc1 = __builtin_amdgcn_mfma_f32_16x16x32_bf16(alo, bh1, acc1, 0, 0, 0);
    }
    float bias0 = Wb[o0 + m], bias1 = Wb[o0 + 16 + m];
    #pragma unroll
    for (int reg = 0; reg < 4; ++reg) {
        int row = quad * 4 + reg;
        whs[row][o0 + m] = acc0[reg] + bias0;
        whs[row][o0 + 16 + m] = acc1[reg] + bias1;
    }
    __syncthreads();
    {   // WhT writer: 2 threads per o, 8 n each
        int o = t >> 1, half = t & 1;
        u16x8 v8;
        #pragma unroll
        for (int r = 0; r < 8; ++r) v8[r] = (short)f2b(whs[half * 8 + r][o]);
        *(u16x8*)(WhT + (size_t)(b * FOUT + o) * NN + n0 + half * 8) = v8;
    }
    {   // e-dots + exp tables
        int outi = t >> 1, half = t & 1;
        int i = outi >> 3, d = outi & 7, hh = d & 3, side = d >> 2;
        const float* arow = attw + hh * (2 * FOUT) + side * FOUT + half * 64;
        float s = 0.f;
        #pragma unroll 8
        for (int k = 0; k < 64; ++k) s = fmaf(whs[i][half * 64 + k], arow[k], s);
        s += __shfl_xor(s, 1);
        if (half == 0) {
            float p = __expf(s), n = __expf(NEG_SLOPE * s);
            if (side == 0) {
                ELpair[(size_t)(b * NH + hh) * NN + n0 + i] = make_float2(p, n);
            } else {
                ERf[((size_t)b * NN + n0 + i) * NH + hh] = make_float2(p, n);
            }
        }
    }
}

// ---------------------------------------------------------------------------
// K2 v5 (measured best: 44 µs, conflicts 0, no spill): register-fragment A
// build; waves = (isub 2) x (kp 4); each wave owns 16 i-rows x ALL 128 o
// (8 B-frags) x ks = kp, kp+4, ... (16 iters). Zero A-build duplication;
// ERf LDS uses BIJECTIVE XOR skew: store g ^ (((g>>4)&3)<<1), read
// (gb+e*2) ^ (quad<<1) -> quads on disjoint bank groups. No main-loop
// barriers. Denominators via ones-MFMA (D-row layout). Tail: 4-way kp
// reduce through reused LDS. grid (NN/32, BB) = 256 blocks x 512 thr.
// ---------------------------------------------------------------------------
__global__ __launch_bounds__(512, 2) void k2_reg(
    const unsigned short* __restrict__ WhT, const float2* __restrict__ ERf,
    const float2* __restrict__ ELpair, const u64* __restrict__ mask,
    float* __restrict__ out) {
    __shared__ char smem[65600 + 8448 + 1536];   // 73.8 KB
    float4* erf4 = (float4*)smem;                // XOR-skewed [4096] float4
    u64* mlds = (u64*)(smem + 65600);            // [32][33] padded
    float* sred = (float*)(smem + 65600 + 8448); // [3kp'][2isub][4h][4r][4quad]
    int t = threadIdx.x;
    int b = blockIdx.y, i0 = blockIdx.x * 32;
    int lane = t & 63, wv = t >> 6;
    int m = lane & 15, quad = lane >> 4;
    int isub = wv & 1, kp = wv >> 1;             // kp in 0..3

    {   // stage ERf for this b (bijective XOR-skewed destination)
        const float4* src = (const float4*)(ERf + (size_t)b * NN * NH);
        #pragma unroll
        for (int i = 0; i < 8; ++i) {
            int g = t + i * 512;
            erf4[g ^ (((g >> 4) & 3) << 1)] = src[g];
        }
    }
    {   // stage masks: 32 rows x 32 words, padded stride 33
        #pragma unroll
        for (int i = 0; i < 2; ++i) {
            int idx = t + i * 512;
            int r = idx >> 5, w = idx & 31;
            mlds[r * 33 + w] = mask[(size_t)(i0 + r) * 32 + w];
        }
    }
    int irow = i0 + isub * 16 + m;               // this lane's A row
    float elp[NH], eln[NH];
    #pragma unroll
    for (int hh = 0; hh < NH; ++hh) {
        float2 e2 = ELpair[(size_t)(b * NH + hh) * NN + irow];
        elp[hh] = e2.x; eln[hh] = e2.y;
    }
    __syncthreads();

    bf16x8 ones;
    #pragma unroll
    for (int e = 0; e < 8; ++e) ones[e] = (short)0x3F80;   // bf16 1.0

    const unsigned short* bp[8];
    #pragma unroll
    for (int f = 0; f < 8; ++f)
        bp[f] = WhT + (size_t)(b * FOUT + f * 16 + m) * NN + kp * 32 + quad * 8;

    f32x4 acc[8][NH];                            // [o-frag f][head h]
    f32x4 sacc[NH];                              // [head h] denominator
    #pragma unroll
    for (int f = 0; f < 8; ++f)
        #pragma unroll
        for (int hh = 0; hh < NH; ++hh) acc[f][hh] = (f32x4){0.f, 0.f, 0.f, 0.f};
    #pragma unroll
    for (int hh = 0; hh < NH; ++hh) sacc[hh] = (f32x4){0.f, 0.f, 0.f, 0.f};

    int mr = isub * 16 + m;                      // local mask row
    int qs = quad << 1;                          // XOR skew for reads

    for (int it = 0; it < 16; ++it) {
        int ks = (it << 2) | kp;
        int jb = ks * 32 + quad * 8;             // lane's 8-j window
        bf16x8 bfr[8];
        #pragma unroll
        for (int f = 0; f < 8; ++f) bfr[f] = *(const bf16x8*)(bp[f]);
        u64 w64 = mlds[mr * 33 + (ks >> 1)];
        unsigned mb = (unsigned)(w64 >> (((ks & 1) << 5) + (quad << 3))) & 0xFFu;
        int gb = jb * 2;                         // unskewed float4 base (mod16==0)
        bf16x8 af0, af1, af2, af3;
        #pragma unroll
        for (int e = 0; e < 8; ++e) {
            int a0 = (gb + e * 2) ^ qs;          // (g>>4)&3 == quad here
            float4 e0 = erf4[a0];                // h0p h0n h1p h1n
            float4 e1 = erf4[a0 + 1];            // h2p h2n h3p h3n
            bool bit = (mb >> e) & 1u;
            float w0 = fmaxf(elp[0] * e0.x, eln[0] * e0.y);
            float w1 = fmaxf(elp[1] * e0.z, eln[1] * e0.w);
            float w2 = fmaxf(elp[2] * e1.x, eln[2] * e1.y);
            float w3 = fmaxf(elp[3] * e1.z, eln[3] * e1.w);
            af0[e] = bit ? (short)f2b_fast(w0) : (short)0;
            af1[e] = bit ? (short)f2b_fast(w1) : (short)0;
            af2[e] = bit ? (short)f2b_fast(w2) : (short)0;
            af3[e] = bit ? (short)f2b_fast(w3) : (short)0;
        }
        sacc[0] = __builtin_amdgcn_mfma_f32_16x16x32_bf16(af0, ones, sacc[0], 0, 0, 0);
        sacc[1] = __builtin_amdgcn_mfma_f32_16x16x32_bf16(af1, ones, sacc[1], 0, 0, 0);
        sacc[2] = __builtin_amdgcn_mfma_f32_16x16x32_bf16(af2, ones, sacc[2], 0, 0, 0);
        sacc[3] = __builtin_amdgcn_mfma_f32_16x16x32_bf16(af3, ones, sacc[3], 0, 0, 0);
        #pragma unroll
        for (int f = 0; f < 8; ++f) {
            acc[f][0] = __builtin_amdgcn_mfma_f32_16x16x32_bf16(af0, bfr[f], acc[f][0], 0, 0, 0);
            acc[f][1] = __builtin_amdgcn_mfma_f32_16x16x32_bf16(af1, bfr[f], acc[f][1], 0, 0, 0);
            acc[f][2] = __builtin_amdgcn_mfma_f32_16x16x32_bf16(af2, bfr[f], acc[f][2], 0, 0, 0);
            acc[f][3] = __builtin_amdgcn_mfma_f32_16x16x32_bf16(af3, bfr[f], acc[f][3], 0, 0, 0);
        }
        #pragma unroll
        for (int f = 0; f < 8; ++f) bp[f] += 128;
    }
    __syncthreads();                             // ERf reads done; reuse smem

    // ---- tail: 4-way kp reduction. red reuses erf4 region (48 KB).
    float* red = (float*)smem;                   // [3kp'][2isub][8f][4r][64]
    if (kp && m == 0) {
        #pragma unroll
        for (int hh = 0; hh < NH; ++hh)
            #pragma unroll
            for (int r = 0; r < 4; ++r)
                sred[(((kp - 1) * 2 + isub) * 16 + hh * 4 + r) * 4 + quad] = sacc[hh][r];
    }
    float v[8][4], inv[4][4];
    #pragma unroll
    for (int hh = 0; hh < NH; ++hh) {
        if (kp) {
            #pragma unroll
            for (int f = 0; f < 8; ++f)
                #pragma unroll
                for (int r = 0; r < 4; ++r)
                    red[((((kp - 1) * 2 + isub) * 8 + f) * 4 + r) * 64 + lane] = acc[f][hh][r];
        }
        __syncthreads();
        if (kp == 0) {
            if (hh == 0) {
                #pragma unroll
                for (int h2 = 0; h2 < NH; ++h2)
                    #pragma unroll
                    for (int r = 0; r < 4; ++r) {
                        float S = sacc[h2][r];
                        #pragma unroll
                        for (int k2 = 0; k2 < 3; ++k2)
                            S += sred[((k2 * 2 + isub) * 16 + h2 * 4 + r) * 4 + quad];
                        inv[h2][r] = (S > 0.f) ? 1.f / S : 0.f;
                    }
            }
            #pragma unroll
            for (int f = 0; f < 8; ++f)
                #pragma unroll
                for (int r = 0; r < 4; ++r) {
                    float tot = acc[f][hh][r];
                    #pragma unroll
                    for (int k2 = 0; k2 < 3; ++k2)
                        tot += red[(((k2 * 2 + isub) * 8 + f) * 4 + r) * 64 + lane];
                    float t2 = tot * inv[hh][r];
                    if (hh == 0) v[f][r] = t2; else v[f][r] += t2;
                }
        }
        __syncthreads();
    }
    if (kp == 0) {
        #pragma unroll
        for (int r = 0; r < 4; ++r) {
            int orow = i0 + isub * 16 + quad * 4 + r;
            #pragma unroll
            for (int f = 0; f < 8; ++f)
                out[((size_t)b * NN + orow) * FOUT + f * 16 + m] =
                    fmaxf(0.25f * v[f][r], 0.f);
        }
    }
}

extern "C" void kernel_launch(void* const* d_in, const int* in_sizes, int n_in,
                              void* d_out, int out_size, void* d_ws, size_t ws_size,
                              hipStream_t stream) {
    const float* h    = (const float*)d_in[0];
    const int* adj    = (const int*)d_in[1];
    const float* Ww   = (const float*)d_in[2];
    const float* Wb   = (const float*)d_in[3];
    const float* attw = (const float*)d_in[4];
    float* out = (float*)d_out;
    char* ws = (char*)d_ws;
    // workspace layout (~3.3 MB)
    unsigned short* Whi = (unsigned short*)(ws);                 // 64 KB
    unsigned short* Wlo = (unsigned short*)(ws + 65536);         // 64 KB
    unsigned short* WhT = (unsigned short*)(ws + 131072);        // 2 MB [b][o][n] bf16
    float2*       ELpair = (float2*)(ws + 2228224);              // 256 KB [bh][i]
    float2*       ERf    = (float2*)(ws + 2490368);              // 256 KB [b][j][h] f32 pair
    u64*          mask   = (u64*)(ws + 2752512);                 // 512 KB

    k0_prep<<<dim3(128), dim3(256), 0, stream>>>(Ww, Whi, Wlo);
    k1_wh<<<dim3(BB * NN / 16 + NN), dim3(256), 0, stream>>>(h, Whi, Wlo, Wb, attw,
                                                             WhT, ELpair, ERf,
                                                             adj, mask);
    k2_reg<<<dim3(NN / 32, BB), dim3(512), 0, stream>>>(WhT, ERf, ELpair,
                                                        mask, out);
}